// Round 1
// baseline (213.350 us; speedup 1.0000x reference)
//
#include <hip/hip_runtime.h>
#include <hip/hip_bf16.h>

#define N_NODES 4096
#define D_MODEL 256
#define NWORDS 128   // bitmap words per row (4096/32)

// ---------------- LayerNorm: one block (256 thr) per row ----------------
__global__ __launch_bounds__(256) void ln_kernel(const float* __restrict__ x,
                                                 const float* __restrict__ g,
                                                 const float* __restrict__ b,
                                                 float* __restrict__ out) {
    int row = blockIdx.x, t = threadIdx.x;
    float v = x[row * D_MODEL + t];
    __shared__ float red[4];
    float s = v;
    #pragma unroll
    for (int off = 32; off; off >>= 1) s += __shfl_down(s, off, 64);
    if ((t & 63) == 0) red[t >> 6] = s;
    __syncthreads();
    float mu = (red[0] + red[1] + red[2] + red[3]) * (1.0f / 256.0f);
    __syncthreads();
    float d = v - mu;
    float s2 = d * d;
    #pragma unroll
    for (int off = 32; off; off >>= 1) s2 += __shfl_down(s2, off, 64);
    if ((t & 63) == 0) red[t >> 6] = s2;
    __syncthreads();
    float var = (red[0] + red[1] + red[2] + red[3]) * (1.0f / 256.0f);
    out[row * D_MODEL + t] = d * rsqrtf(var + 1e-5f) * g[t] + b[t];
}

// ---------------- edge dtype detect: int64 arrays have 0 high words ------
__global__ void detect_kernel(const int* __restrict__ ei, int* __restrict__ flag) {
    if (threadIdx.x == 0 && blockIdx.x == 0) {
        int is64 = 1;
        for (int i = 1; i < 128; i += 2)
            if (ei[i] != 0) { is64 = 0; break; }
        *flag = is64;
    }
}

// ---------------- build dedup'd adjacency bitmap --------------------------
__global__ __launch_bounds__(256) void build_adj(const int* __restrict__ ei, int E,
                                                 const int* __restrict__ flag,
                                                 unsigned* __restrict__ bitmap) {
    int e = blockIdx.x * blockDim.x + threadIdx.x;
    if (e >= E) return;
    int n, m;
    if (*flag) {           // int64 layout: low words at even int32 indices
        n = ei[2 * e];
        m = ei[2 * (E + e)];
    } else {               // int32 layout
        n = ei[e];
        m = ei[E + e];
    }
    atomicOr(&bitmap[n * NWORDS + (m >> 5)], 1u << (m & 31));
}

// ---------------- fp32 tiled GEMM, fused epilogue --------------------------
// C[NrowsxM] = A[NrowsxK] @ B[KxM] + bias; MODE 0: plain, 1: exact GELU, 2: +R
template <int MODE>
__global__ __launch_bounds__(256) void gemm_kernel(const float* __restrict__ A,
                                                   const float* __restrict__ B,
                                                   const float* __restrict__ bias,
                                                   const float* __restrict__ R,
                                                   float* __restrict__ C,
                                                   int K, int M) {
    __shared__ float As[16][64];   // [k][row]
    __shared__ float Bs[16][64];   // [k][col]
    int tid  = threadIdx.x;
    int brow = blockIdx.x * 64;
    int bcol = blockIdx.y * 64;
    int tx = tid & 15, ty = tid >> 4;
    int ar = tid >> 2, ac = (tid & 3) << 2;      // A tile: 64 rows x 16 k
    int br = tid >> 4, bc = (tid & 15) << 2;     // B tile: 16 k x 64 cols
    float acc[4][4] = {};
    for (int k0 = 0; k0 < K; k0 += 16) {
        float4 a4 = *(const float4*)&A[(brow + ar) * K + k0 + ac];
        As[ac + 0][ar] = a4.x;
        As[ac + 1][ar] = a4.y;
        As[ac + 2][ar] = a4.z;
        As[ac + 3][ar] = a4.w;
        *(float4*)&Bs[br][bc] = *(const float4*)&B[(k0 + br) * M + bcol + bc];
        __syncthreads();
        #pragma unroll
        for (int kk = 0; kk < 16; ++kk) {
            float4 av = *(const float4*)&As[kk][ty << 2];
            float4 bv = *(const float4*)&Bs[kk][tx << 2];
            float a_[4] = {av.x, av.y, av.z, av.w};
            float b_[4] = {bv.x, bv.y, bv.z, bv.w};
            #pragma unroll
            for (int i = 0; i < 4; ++i)
                #pragma unroll
                for (int j = 0; j < 4; ++j)
                    acc[i][j] = fmaf(a_[i], b_[j], acc[i][j]);
        }
        __syncthreads();
    }
    #pragma unroll
    for (int i = 0; i < 4; ++i) {
        int row = brow + (ty << 2) + i;
        #pragma unroll
        for (int j = 0; j < 4; ++j) {
            int col = bcol + (tx << 2) + j;
            float c = acc[i][j] + bias[col];
            if (MODE == 1) c = 0.5f * c * (1.0f + erff(c * 0.70710678118654752f));
            if (MODE == 2) c += R[row * M + col];
            C[row * M + col] = c;
        }
    }
}

// ---------------- sparse masked attention ---------------------------------
// 1 block (256 thr) per query row n; 8 head-groups of 32 lanes; online softmax
__global__ __launch_bounds__(256) void attn_kernel(const float* __restrict__ q,
                                                   const float* __restrict__ k,
                                                   const float* __restrict__ v,
                                                   const unsigned* __restrict__ bitmap,
                                                   float* __restrict__ y) {
    int n = blockIdx.x, t = threadIdx.x;
    float qv = q[n * D_MODEL + t] * 0.17677669529663687f;  // 1/sqrt(32)
    float Mx = -3.0e38f, S = 0.0f, acc = 0.0f;
    for (int w = 0; w < NWORDS; ++w) {
        unsigned word = bitmap[n * NWORDS + w];
        while (word) {
            int bit = __ffs(word) - 1;
            word &= word - 1;
            int m = (w << 5) + bit;
            float s = qv * k[m * D_MODEL + t];
            #pragma unroll
            for (int off = 16; off; off >>= 1) s += __shfl_xor(s, off, 32);
            float vv = v[m * D_MODEL + t];
            float newM = fmaxf(Mx, s);
            float rescale = __expf(Mx - newM);
            float p = __expf(s - newM);
            acc = acc * rescale + p * vv;
            S = S * rescale + p;
            Mx = newM;
        }
    }
    y[n * D_MODEL + t] = acc / S;
}

extern "C" void kernel_launch(void* const* d_in, const int* in_sizes, int n_in,
                              void* d_out, int out_size, void* d_ws, size_t ws_size,
                              hipStream_t stream) {
    const float* x   = (const float*)d_in[0];
    const int*   ei  = (const int*)d_in[1];
    const float* Wq  = (const float*)d_in[2];  const float* bq  = (const float*)d_in[3];
    const float* Wk  = (const float*)d_in[4];  const float* bk  = (const float*)d_in[5];
    const float* Wv  = (const float*)d_in[6];  const float* bv  = (const float*)d_in[7];
    const float* Wo  = (const float*)d_in[8];  const float* bo  = (const float*)d_in[9];
    const float* g1  = (const float*)d_in[10]; const float* b1  = (const float*)d_in[11];
    const float* g2  = (const float*)d_in[12]; const float* b2  = (const float*)d_in[13];
    const float* Wm1 = (const float*)d_in[14]; const float* bm1 = (const float*)d_in[15];
    const float* Wm2 = (const float*)d_in[16]; const float* bm2 = (const float*)d_in[17];
    float* out = (float*)d_out;
    int E = in_sizes[1] / 2;   // 135168

    const size_t SLOT = (size_t)N_NODES * D_MODEL;  // 1M floats = 4MB
    float* ws  = (float*)d_ws;
    float* h   = ws;                 // LN1 out, later LN2 out
    float* q   = ws + 1 * SLOT;
    float* kb  = ws + 2 * SLOT;
    float* vb  = ws + 3 * SLOT;
    float* y   = ws + 4 * SLOT;
    unsigned* bitmap = (unsigned*)(ws + 5 * SLOT);          // 2MB
    int* flag = (int*)(ws + 5 * SLOT + N_NODES * NWORDS);   // 4B
    float* x1  = vb;   // reuse v after attention
    float* m1  = q;    // reuse q+k (8MB) for MLP intermediate [4096,512]

    hipMemsetAsync(bitmap, 0, (size_t)N_NODES * NWORDS * sizeof(unsigned), stream);
    detect_kernel<<<1, 64, 0, stream>>>(ei, flag);
    ln_kernel<<<N_NODES, 256, 0, stream>>>(x, g1, b1, h);
    build_adj<<<(E + 255) / 256, 256, 0, stream>>>(ei, E, flag, bitmap);

    dim3 g256(N_NODES / 64, 4), g512(N_NODES / 64, 8);
    gemm_kernel<0><<<g256, 256, 0, stream>>>(h, Wq, bq, nullptr, q, 256, 256);
    gemm_kernel<0><<<g256, 256, 0, stream>>>(h, Wk, bk, nullptr, kb, 256, 256);
    gemm_kernel<0><<<g256, 256, 0, stream>>>(h, Wv, bv, nullptr, vb, 256, 256);

    attn_kernel<<<N_NODES, 256, 0, stream>>>(q, kb, vb, bitmap, y);

    gemm_kernel<2><<<g256, 256, 0, stream>>>(y, Wo, bo, x, x1, 256, 256);
    ln_kernel<<<N_NODES, 256, 0, stream>>>(x1, g2, b2, h);
    gemm_kernel<1><<<g512, 256, 0, stream>>>(h, Wm1, bm1, nullptr, m1, 256, 512);
    gemm_kernel<2><<<g256, 256, 0, stream>>>(m1, Wm2, bm2, x1, out, 512, 256);
}

// Round 2
// 138.138 us; speedup vs baseline: 1.5445x; 1.5445x over previous
//
#include <hip/hip_runtime.h>
#include <hip/hip_bf16.h>

#define N_NODES 4096
#define D_MODEL 256
#define NWORDS 128   // bitmap words per row (4096/32)

typedef __attribute__((ext_vector_type(8))) short short8;
typedef __attribute__((ext_vector_type(4))) float f32x4;

__device__ __forceinline__ unsigned short f2b(float f) {  // fp32 -> bf16 RTN
    unsigned u = __float_as_uint(f);
    return (unsigned short)((u + 0x7FFFu + ((u >> 16) & 1u)) >> 16);
}

// ---------------- LayerNorm: one block (256 thr) per row, bf16 out -------
__global__ __launch_bounds__(256) void ln_kernel(const float* __restrict__ x,
                                                 const float* __restrict__ g,
                                                 const float* __restrict__ b,
                                                 unsigned short* __restrict__ out) {
    int row = blockIdx.x, t = threadIdx.x;
    float v = x[row * D_MODEL + t];
    __shared__ float red[4];
    float s = v;
    #pragma unroll
    for (int off = 32; off; off >>= 1) s += __shfl_down(s, off, 64);
    if ((t & 63) == 0) red[t >> 6] = s;
    __syncthreads();
    float mu = (red[0] + red[1] + red[2] + red[3]) * (1.0f / 256.0f);
    __syncthreads();
    float d = v - mu;
    float s2 = d * d;
    #pragma unroll
    for (int off = 32; off; off >>= 1) s2 += __shfl_down(s2, off, 64);
    if ((t & 63) == 0) red[t >> 6] = s2;
    __syncthreads();
    float var = (red[0] + red[1] + red[2] + red[3]) * (1.0f / 256.0f);
    out[row * D_MODEL + t] = f2b(d * rsqrtf(var + 1e-5f) * g[t] + b[t]);
}

// ---------------- edge dtype detect: int64 arrays have 0 high words ------
__global__ void detect_kernel(const int* __restrict__ ei, int* __restrict__ flag) {
    if (threadIdx.x == 0 && blockIdx.x == 0) {
        int is64 = 1;
        for (int i = 1; i < 128; i += 2)
            if (ei[i] != 0) { is64 = 0; break; }
        *flag = is64;
    }
}

// ---------------- build dedup'd adjacency bitmap --------------------------
__global__ __launch_bounds__(256) void build_adj(const int* __restrict__ ei, int E,
                                                 const int* __restrict__ flag,
                                                 unsigned* __restrict__ bitmap) {
    int e = blockIdx.x * blockDim.x + threadIdx.x;
    if (e >= E) return;
    int n, m;
    if (*flag) { n = ei[2 * e]; m = ei[2 * (E + e)]; }
    else       { n = ei[e];     m = ei[E + e]; }
    atomicOr(&bitmap[n * NWORDS + (m >> 5)], 1u << (m & 31));
}

// ---------------- weights: fp32 [K][M] -> bf16 transposed [M][K] ----------
// regions: Wq,Wk,Wv,Wo (256x256), Wm1 (256x512), Wm2 (512x256)
__global__ __launch_bounds__(256) void convw_kernel(const float* __restrict__ Wq,
        const float* __restrict__ Wk, const float* __restrict__ Wv,
        const float* __restrict__ Wo, const float* __restrict__ Wm1,
        const float* __restrict__ Wm2, unsigned short* __restrict__ wbf) {
    int e = blockIdx.x * 256 + threadIdx.x;   // 0..524287
    const float* W; int base, K, M;
    if (e < 262144) {
        int r = e >> 16;
        W = (r == 0) ? Wq : (r == 1) ? Wk : (r == 2) ? Wv : Wo;
        base = r << 16; K = 256; M = 256;
    } else if (e < 393216) { W = Wm1; base = 262144; K = 256; M = 512; }
    else                   { W = Wm2; base = 393216; K = 512; M = 256; }
    int i = e - base;
    int m = i / K, k = i - m * K;
    wbf[e] = f2b(W[k * M + m]);   // WT[m][k], row-major [M][K]
}

// ---------------- bf16 MFMA GEMM: C[rows x M] = A @ B (+epilogue) ---------
// A: [rows][K] bf16 row-major. BT: [M][K] bf16 row-major (B transposed).
// 64x64 tile, BK=32, 4 waves each 32x32. MODE 0: bias->f32. 1: gelu->bf16.
// 2: bias+R->f32.
template <int MODE>
__global__ __launch_bounds__(256) void gemm_bf16(const unsigned short* __restrict__ A,
        const unsigned short* __restrict__ BT, const float* __restrict__ bias,
        const float* __restrict__ R, float* __restrict__ Cf,
        unsigned short* __restrict__ Cb, int K, int M) {
    __shared__ unsigned short Al[64][40];   // stride 40 (80B) -> no 2^k conflicts
    __shared__ unsigned short Bl[64][40];
    int tid = threadIdx.x;
    int brow = blockIdx.x * 64, bcol = blockIdx.y * 64;
    int wid = tid >> 6, lane = tid & 63;
    int wr = wid >> 1, wc = wid & 1;              // wave sub-tile (32x32)
    int l15 = lane & 15, lhi = lane >> 4;
    int srow = tid >> 2, scol = (tid & 3) << 3;   // staging: 64 rows x 4 thr
    const unsigned short* Ap = A + (size_t)(brow + srow) * K + scol;
    const unsigned short* Bp = BT + (size_t)(bcol + srow) * K + scol;
    f32x4 acc[2][2] = {};
    for (int k0 = 0; k0 < K; k0 += 32) {
        short8 av = *(const short8*)(Ap + k0);
        short8 bv = *(const short8*)(Bp + k0);
        *(short8*)&Al[srow][scol] = av;
        *(short8*)&Bl[srow][scol] = bv;
        __syncthreads();
        short8 a0 = *(const short8*)&Al[wr * 32 + l15][lhi * 8];
        short8 a1 = *(const short8*)&Al[wr * 32 + 16 + l15][lhi * 8];
        short8 b0 = *(const short8*)&Bl[wc * 32 + l15][lhi * 8];
        short8 b1 = *(const short8*)&Bl[wc * 32 + 16 + l15][lhi * 8];
        acc[0][0] = __builtin_amdgcn_mfma_f32_16x16x32_bf16(a0, b0, acc[0][0], 0, 0, 0);
        acc[0][1] = __builtin_amdgcn_mfma_f32_16x16x32_bf16(a0, b1, acc[0][1], 0, 0, 0);
        acc[1][0] = __builtin_amdgcn_mfma_f32_16x16x32_bf16(a1, b0, acc[1][0], 0, 0, 0);
        acc[1][1] = __builtin_amdgcn_mfma_f32_16x16x32_bf16(a1, b1, acc[1][1], 0, 0, 0);
        __syncthreads();
    }
    #pragma unroll
    for (int sm = 0; sm < 2; ++sm)
        #pragma unroll
        for (int sn = 0; sn < 2; ++sn) {
            int col = bcol + wc * 32 + sn * 16 + l15;
            float bs = bias[col];
            #pragma unroll
            for (int r = 0; r < 4; ++r) {
                int row = brow + wr * 32 + sm * 16 + lhi * 4 + r;
                float c = acc[sm][sn][r] + bs;
                if (MODE == 1) {
                    c = 0.5f * c * (1.0f + erff(c * 0.70710678118654752f));
                    Cb[(size_t)row * M + col] = f2b(c);
                } else if (MODE == 2) {
                    Cf[(size_t)row * M + col] = c + R[(size_t)row * M + col];
                } else {
                    Cf[(size_t)row * M + col] = c;
                }
            }
        }
}

// ---------------- sparse masked attention (unchanged math, bf16 y) --------
__global__ __launch_bounds__(256) void attn_kernel(const float* __restrict__ q,
                                                   const float* __restrict__ k,
                                                   const float* __restrict__ v,
                                                   const unsigned* __restrict__ bitmap,
                                                   unsigned short* __restrict__ y) {
    int n = blockIdx.x, t = threadIdx.x;
    float qv = q[n * D_MODEL + t] * 0.17677669529663687f;  // 1/sqrt(32)
    float Mx = -3.0e38f, S = 0.0f, acc = 0.0f;
    for (int w = 0; w < NWORDS; ++w) {
        unsigned word = bitmap[n * NWORDS + w];
        while (word) {
            int bit = __ffs(word) - 1;
            word &= word - 1;
            int m = (w << 5) + bit;
            float s = qv * k[m * D_MODEL + t];
            #pragma unroll
            for (int off = 16; off; off >>= 1) s += __shfl_xor(s, off, 32);
            float vv = v[m * D_MODEL + t];
            float newM = fmaxf(Mx, s);
            float rescale = __expf(Mx - newM);
            float p = __expf(s - newM);
            acc = acc * rescale + p * vv;
            S = S * rescale + p;
            Mx = newM;
        }
    }
    y[n * D_MODEL + t] = f2b(acc / S);
}

extern "C" void kernel_launch(void* const* d_in, const int* in_sizes, int n_in,
                              void* d_out, int out_size, void* d_ws, size_t ws_size,
                              hipStream_t stream) {
    const float* x   = (const float*)d_in[0];
    const int*   ei  = (const int*)d_in[1];
    const float* Wq  = (const float*)d_in[2];  const float* bq  = (const float*)d_in[3];
    const float* Wk  = (const float*)d_in[4];  const float* bk  = (const float*)d_in[5];
    const float* Wv  = (const float*)d_in[6];  const float* bv  = (const float*)d_in[7];
    const float* Wo  = (const float*)d_in[8];  const float* bo  = (const float*)d_in[9];
    const float* g1  = (const float*)d_in[10]; const float* b1  = (const float*)d_in[11];
    const float* g2  = (const float*)d_in[12]; const float* b2  = (const float*)d_in[13];
    const float* Wm1 = (const float*)d_in[14]; const float* bm1 = (const float*)d_in[15];
    const float* Wm2 = (const float*)d_in[16]; const float* bm2 = (const float*)d_in[17];
    float* out = (float*)d_out;
    int E = in_sizes[1] / 2;   // 135168

    char* WS = (char*)d_ws;
    unsigned*       bitmap = (unsigned*)WS;                           // [0,2MB)
    unsigned short* wbf    = (unsigned short*)(WS + (2u << 20));      // [2,3MB)
    int*            flag   = (int*)(WS + (3u << 20));                 // 4B
    unsigned short* h      = (unsigned short*)(WS + (4u << 20));      // [4,6MB) bf16
    float*          q      = (float*)(WS + (8u << 20));               // [8,12MB)
    float*          kb     = (float*)(WS + (12u << 20));              // [12,16MB)
    float*          vb     = (float*)(WS + (16u << 20));              // [16,20MB)
    unsigned short* y      = (unsigned short*)(WS + (20u << 20));     // [20,22MB)
    float*          x1     = (float*)(WS + (8u << 20));               // alias q
    unsigned short* h2     = (unsigned short*)(WS + (12u << 20));     // alias kb
    unsigned short* m1     = (unsigned short*)(WS + (14u << 20));     // [14,18MB)

    const unsigned short* WTq  = wbf;
    const unsigned short* WTk  = wbf + 65536;
    const unsigned short* WTv  = wbf + 131072;
    const unsigned short* WTo  = wbf + 196608;
    const unsigned short* WTm1 = wbf + 262144;
    const unsigned short* WTm2 = wbf + 393216;

    hipMemsetAsync(bitmap, 0, (size_t)N_NODES * NWORDS * sizeof(unsigned), stream);
    detect_kernel<<<1, 64, 0, stream>>>(ei, flag);
    convw_kernel<<<2048, 256, 0, stream>>>(Wq, Wk, Wv, Wo, Wm1, Wm2, wbf);
    ln_kernel<<<N_NODES, 256, 0, stream>>>(x, g1, b1, h);
    build_adj<<<(E + 255) / 256, 256, 0, stream>>>(ei, E, flag, bitmap);

    dim3 g256(N_NODES / 64, 4), g512(N_NODES / 64, 8);
    gemm_bf16<0><<<g256, 256, 0, stream>>>(h, WTq, bq, nullptr, q, nullptr, 256, 256);
    gemm_bf16<0><<<g256, 256, 0, stream>>>(h, WTk, bk, nullptr, kb, nullptr, 256, 256);
    gemm_bf16<0><<<g256, 256, 0, stream>>>(h, WTv, bv, nullptr, vb, nullptr, 256, 256);

    attn_kernel<<<N_NODES, 256, 0, stream>>>(q, kb, vb, bitmap, y);

    gemm_bf16<2><<<g256, 256, 0, stream>>>(y, WTo, bo, x, x1, nullptr, 256, 256);
    ln_kernel<<<N_NODES, 256, 0, stream>>>(x1, g2, b2, h2);
    gemm_bf16<1><<<g512, 256, 0, stream>>>(h2, WTm1, bm1, nullptr, nullptr, m1, 256, 512);
    gemm_bf16<2><<<g256, 256, 0, stream>>>(m1, WTm2, bm2, x1, out, nullptr, 512, 256);
}

// Round 3
// 105.928 us; speedup vs baseline: 2.0141x; 1.3041x over previous
//
#include <hip/hip_runtime.h>
#include <hip/hip_bf16.h>

#define N_NODES 4096
#define D_MODEL 256
#define NWORDS 128   // bitmap words per row (4096/32)
#define MAXC 512     // max neighbors per row (avg ~33; Poisson tail safe)

typedef __attribute__((ext_vector_type(8))) short short8;
typedef __attribute__((ext_vector_type(4))) float f32x4;

__device__ __forceinline__ unsigned short f2b(float f) {  // fp32 -> bf16 RTN
    unsigned u = __float_as_uint(f);
    return (unsigned short)((u + 0x7FFFu + ((u >> 16) & 1u)) >> 16);
}
__device__ __forceinline__ float b2f(unsigned short u) {
    return __uint_as_float((unsigned)u << 16);
}

// ---------------- LayerNorm: one block (256 thr) per row, bf16 out -------
__global__ __launch_bounds__(256) void ln_kernel(const float* __restrict__ x,
                                                 const float* __restrict__ g,
                                                 const float* __restrict__ b,
                                                 unsigned short* __restrict__ out) {
    int row = blockIdx.x, t = threadIdx.x;
    float v = x[row * D_MODEL + t];
    __shared__ float red[4];
    float s = v;
    #pragma unroll
    for (int off = 32; off; off >>= 1) s += __shfl_down(s, off, 64);
    if ((t & 63) == 0) red[t >> 6] = s;
    __syncthreads();
    float mu = (red[0] + red[1] + red[2] + red[3]) * (1.0f / 256.0f);
    __syncthreads();
    float d = v - mu;
    float s2 = d * d;
    #pragma unroll
    for (int off = 32; off; off >>= 1) s2 += __shfl_down(s2, off, 64);
    if ((t & 63) == 0) red[t >> 6] = s2;
    __syncthreads();
    float var = (red[0] + red[1] + red[2] + red[3]) * (1.0f / 256.0f);
    out[row * D_MODEL + t] = f2b(d * rsqrtf(var + 1e-5f) * g[t] + b[t]);
}

// ---------------- edge dtype detect: int64 arrays have 0 high words ------
__global__ void detect_kernel(const int* __restrict__ ei, int* __restrict__ flag) {
    if (threadIdx.x == 0 && blockIdx.x == 0) {
        int is64 = 1;
        for (int i = 1; i < 128; i += 2)
            if (ei[i] != 0) { is64 = 0; break; }
        *flag = is64;
    }
}

// ---------------- build dedup'd adjacency bitmap --------------------------
__global__ __launch_bounds__(256) void build_adj(const int* __restrict__ ei, int E,
                                                 const int* __restrict__ flag,
                                                 unsigned* __restrict__ bitmap) {
    int e = blockIdx.x * blockDim.x + threadIdx.x;
    if (e >= E) return;
    int n, m;
    if (*flag) { n = ei[2 * e]; m = ei[2 * (E + e)]; }
    else       { n = ei[e];     m = ei[E + e]; }
    atomicOr(&bitmap[n * NWORDS + (m >> 5)], 1u << (m & 31));
}

// ---------------- bitmap -> CSR (order-preserving, deterministic) ---------
__global__ __launch_bounds__(128) void csr_kernel(const unsigned* __restrict__ bitmap,
                                                  int* __restrict__ csr,
                                                  int* __restrict__ cnt) {
    int row = blockIdx.x, t = threadIdx.x;   // t = word index 0..127
    unsigned word = bitmap[row * NWORDS + t];
    int pc = __popc(word);
    int pre = pc;                             // inclusive prefix within wave
    #pragma unroll
    for (int off = 1; off < 64; off <<= 1) {
        int u = __shfl_up(pre, off, 64);
        if ((t & 63) >= off) pre += u;
    }
    __shared__ int wsum[2];
    if ((t & 63) == 63) wsum[t >> 6] = pre;
    __syncthreads();
    int base = (t >= 64) ? wsum[0] : 0;
    int off = base + pre - pc;                // exclusive prefix across 128
    int* dst = csr + (size_t)row * MAXC;
    while (word) {
        int bit = __ffs(word) - 1;
        word &= word - 1;
        if (off < MAXC) dst[off] = (t << 5) + bit;
        ++off;
    }
    if (t == 127) cnt[row] = min(base + pre, MAXC);
}

// ---------------- weights: fp32 [K][M] -> bf16 transposed [M][K] ----------
__global__ __launch_bounds__(256) void convw_kernel(const float* __restrict__ Wq,
        const float* __restrict__ Wk, const float* __restrict__ Wv,
        const float* __restrict__ Wo, const float* __restrict__ Wm1,
        const float* __restrict__ Wm2, unsigned short* __restrict__ wbf) {
    int e = blockIdx.x * 256 + threadIdx.x;   // 0..524287
    const float* W; int base, K, M;
    if (e < 262144) {
        int r = e >> 16;
        W = (r == 0) ? Wq : (r == 1) ? Wk : (r == 2) ? Wv : Wo;
        base = r << 16; K = 256; M = 256;
    } else if (e < 393216) { W = Wm1; base = 262144; K = 256; M = 512; }
    else                   { W = Wm2; base = 393216; K = 512; M = 256; }
    int i = e - base;
    int m = i / K, k = i - m * K;
    wbf[e] = f2b(W[k * M + m]);   // WT[m][k], row-major [M][K]
}

// ---------------- bf16 MFMA GEMM ------------------------------------------
// A:[rows][K] bf16. BT:[M][K] bf16. 64x64 tile, BK=32, 4 waves of 32x32.
// MODE 0: +bias -> f32 | 1: +bias,GELU -> bf16 | 2: +bias+R -> f32
// MODE 3: qkv 3-part bias -> bf16
template <int MODE>
__global__ __launch_bounds__(256) void gemm_bf16(const unsigned short* __restrict__ A,
        const unsigned short* __restrict__ BT, const float* __restrict__ bias,
        const float* __restrict__ bias_k, const float* __restrict__ bias_v,
        const float* __restrict__ R, float* __restrict__ Cf,
        unsigned short* __restrict__ Cb, int K, int M) {
    __shared__ unsigned short Al[64][40];
    __shared__ unsigned short Bl[64][40];
    int tid = threadIdx.x;
    int brow = blockIdx.x * 64, bcol = blockIdx.y * 64;
    int wid = tid >> 6, lane = tid & 63;
    int wr = wid >> 1, wc = wid & 1;
    int l15 = lane & 15, lhi = lane >> 4;
    int srow = tid >> 2, scol = (tid & 3) << 3;
    const unsigned short* Ap = A + (size_t)(brow + srow) * K + scol;
    const unsigned short* Bp = BT + (size_t)(bcol + srow) * K + scol;
    f32x4 acc[2][2] = {};
    for (int k0 = 0; k0 < K; k0 += 32) {
        short8 av = *(const short8*)(Ap + k0);
        short8 bv = *(const short8*)(Bp + k0);
        *(short8*)&Al[srow][scol] = av;
        *(short8*)&Bl[srow][scol] = bv;
        __syncthreads();
        short8 a0 = *(const short8*)&Al[wr * 32 + l15][lhi * 8];
        short8 a1 = *(const short8*)&Al[wr * 32 + 16 + l15][lhi * 8];
        short8 b0 = *(const short8*)&Bl[wc * 32 + l15][lhi * 8];
        short8 b1 = *(const short8*)&Bl[wc * 32 + 16 + l15][lhi * 8];
        acc[0][0] = __builtin_amdgcn_mfma_f32_16x16x32_bf16(a0, b0, acc[0][0], 0, 0, 0);
        acc[0][1] = __builtin_amdgcn_mfma_f32_16x16x32_bf16(a0, b1, acc[0][1], 0, 0, 0);
        acc[1][0] = __builtin_amdgcn_mfma_f32_16x16x32_bf16(a1, b0, acc[1][0], 0, 0, 0);
        acc[1][1] = __builtin_amdgcn_mfma_f32_16x16x32_bf16(a1, b1, acc[1][1], 0, 0, 0);
        __syncthreads();
    }
    #pragma unroll
    for (int sm = 0; sm < 2; ++sm)
        #pragma unroll
        for (int sn = 0; sn < 2; ++sn) {
            int col = bcol + wc * 32 + sn * 16 + l15;
            float bs;
            if (MODE == 3)
                bs = (col < 256) ? bias[col]
                   : (col < 512) ? bias_k[col - 256] : bias_v[col - 512];
            else
                bs = bias[col];
            #pragma unroll
            for (int r = 0; r < 4; ++r) {
                int row = brow + wr * 32 + sm * 16 + lhi * 4 + r;
                float c = acc[sm][sn][r] + bs;
                if (MODE == 1) {
                    c = 0.5f * c * (1.0f + erff(c * 0.70710678118654752f));
                    Cb[(size_t)row * M + col] = f2b(c);
                } else if (MODE == 2) {
                    Cf[(size_t)row * M + col] = c + R[(size_t)row * M + col];
                } else if (MODE == 3) {
                    Cb[(size_t)row * M + col] = f2b(c);
                } else {
                    Cf[(size_t)row * M + col] = c;
                }
            }
        }
}

// ---------------- sparse attention: lanes=neighbors, batch softmax --------
// qkv: [N][768] bf16 (q|k|v). 1 block/row, 8 head-groups of 32 lanes.
__global__ __launch_bounds__(256) void attn_kernel(const unsigned short* __restrict__ qkv,
        const int* __restrict__ csr, const int* __restrict__ cnt,
        unsigned short* __restrict__ y) {
    int n = blockIdx.x, tid = threadIdx.x;
    int h = tid >> 5, lane = tid & 31;
    int c = cnt[n];
    __shared__ int sIdx[MAXC];
    for (int i = tid; i < c; i += 256) sIdx[i] = csr[(size_t)n * MAXC + i];
    __syncthreads();

    const unsigned short* qp = qkv + (size_t)n * 768 + h * 32;
    float qreg[32];
    #pragma unroll
    for (int i = 0; i < 4; ++i) {
        short8 q8 = *(const short8*)(qp + i * 8);
        #pragma unroll
        for (int j = 0; j < 8; ++j) qreg[i * 8 + j] = b2f((unsigned short)q8[j]);
    }
    const float sc = 0.17677669529663687f;   // 1/sqrt(32)
    float m_run = -INFINITY, S = 0.0f, acc = 0.0f;
    for (int b0 = 0; b0 < c; b0 += 32) {
        int j = b0 + lane;
        float s = -INFINITY;
        if (j < c) {
            const unsigned short* kp = qkv + (size_t)sIdx[j] * 768 + 256 + h * 32;
            float d = 0.0f;
            #pragma unroll
            for (int i = 0; i < 4; ++i) {
                short8 k8 = *(const short8*)(kp + i * 8);
                #pragma unroll
                for (int e = 0; e < 8; ++e)
                    d = fmaf(qreg[i * 8 + e], b2f((unsigned short)k8[e]), d);
            }
            s = d * sc;
        }
        float bm = s;
        #pragma unroll
        for (int off = 16; off; off >>= 1) bm = fmaxf(bm, __shfl_xor(bm, off, 32));
        float newM = fmaxf(m_run, bm);
        float p = (j < c) ? __expf(s - newM) : 0.0f;
        float bs = p;
        #pragma unroll
        for (int off = 16; off; off >>= 1) bs += __shfl_xor(bs, off, 32);
        float scale = __expf(m_run - newM);
        S = S * scale + bs;
        acc *= scale;
        int lim = min(32, c - b0);
        const unsigned short* vbase = qkv + 512 + h * 32 + lane;
        #pragma unroll 4
        for (int jj = 0; jj < lim; ++jj) {
            float pj = __shfl(p, jj, 32);
            int m = sIdx[b0 + jj];
            acc = fmaf(pj, b2f(vbase[(size_t)m * 768]), acc);
        }
        m_run = newM;
    }
    y[(size_t)n * 256 + h * 32 + lane] = f2b(acc / S);
}

extern "C" void kernel_launch(void* const* d_in, const int* in_sizes, int n_in,
                              void* d_out, int out_size, void* d_ws, size_t ws_size,
                              hipStream_t stream) {
    const float* x   = (const float*)d_in[0];
    const int*   ei  = (const int*)d_in[1];
    const float* Wq  = (const float*)d_in[2];  const float* bq  = (const float*)d_in[3];
    const float* Wk  = (const float*)d_in[4];  const float* bk  = (const float*)d_in[5];
    const float* Wv  = (const float*)d_in[6];  const float* bv  = (const float*)d_in[7];
    const float* Wo  = (const float*)d_in[8];  const float* bo  = (const float*)d_in[9];
    const float* g1  = (const float*)d_in[10]; const float* b1  = (const float*)d_in[11];
    const float* g2  = (const float*)d_in[12]; const float* b2  = (const float*)d_in[13];
    const float* Wm1 = (const float*)d_in[14]; const float* bm1 = (const float*)d_in[15];
    const float* Wm2 = (const float*)d_in[16]; const float* bm2 = (const float*)d_in[17];
    float* out = (float*)d_out;
    int E = in_sizes[1] / 2;   // 135168

    char* WS = (char*)d_ws;
    const size_t MB = 1u << 20;
    unsigned*       bitmap = (unsigned*)WS;                     // [0,2MB), later y
    unsigned short* y      = (unsigned short*)WS;               // reuse after csr
    int*            flag   = (int*)(WS + 2 * MB);               // 4B
    int*            cnt    = (int*)(WS + 2 * MB + 4096);        // 16KB
    unsigned short* wbf    = (unsigned short*)(WS + 3 * MB);    // 1MB
    int*            csr    = (int*)(WS + 4 * MB);               // 8MB, later x1/m1
    float*          x1     = (float*)(WS + 4 * MB);             // 4MB (post-attn)
    unsigned short* m1     = (unsigned short*)(WS + 8 * MB);    // 4MB (post-attn)
    unsigned short* h      = (unsigned short*)(WS + 12 * MB);   // 2MB, later h2
    unsigned short* h2     = (unsigned short*)(WS + 12 * MB);
    unsigned short* qkv    = (unsigned short*)(WS + 14 * MB);   // 6MB

    const unsigned short* WTqkv = wbf;            // q|k|v stacked along M
    const unsigned short* WTo   = wbf + 196608;
    const unsigned short* WTm1  = wbf + 262144;
    const unsigned short* WTm2  = wbf + 393216;

    hipMemsetAsync(bitmap, 0, (size_t)N_NODES * NWORDS * sizeof(unsigned), stream);
    detect_kernel<<<1, 64, 0, stream>>>(ei, flag);
    convw_kernel<<<2048, 256, 0, stream>>>(Wq, Wk, Wv, Wo, Wm1, Wm2, wbf);
    ln_kernel<<<N_NODES, 256, 0, stream>>>(x, g1, b1, h);
    build_adj<<<(E + 255) / 256, 256, 0, stream>>>(ei, E, flag, bitmap);
    csr_kernel<<<N_NODES, 128, 0, stream>>>(bitmap, csr, cnt);

    dim3 gqkv(N_NODES / 64, 12), g256(N_NODES / 64, 4), g512(N_NODES / 64, 8);
    gemm_bf16<3><<<gqkv, 256, 0, stream>>>(h, WTqkv, bq, bk, bv, nullptr,
                                           nullptr, qkv, 256, 768);

    attn_kernel<<<N_NODES, 256, 0, stream>>>(qkv, csr, cnt, y);

    gemm_bf16<2><<<g256, 256, 0, stream>>>(y, WTo, bo, nullptr, nullptr, x,
                                           x1, nullptr, 256, 256);
    ln_kernel<<<N_NODES, 256, 0, stream>>>(x1, g2, b2, h2);
    gemm_bf16<1><<<g512, 256, 0, stream>>>(h2, WTm1, bm1, nullptr, nullptr, nullptr,
                                           nullptr, m1, 256, 512);
    gemm_bf16<2><<<g256, 256, 0, stream>>>(m1, WTm2, bm2, nullptr, nullptr, x1,
                                           out, nullptr, 512, 256);
}

// Round 4
// 105.799 us; speedup vs baseline: 2.0166x; 1.0012x over previous
//
#include <hip/hip_runtime.h>
#include <hip/hip_bf16.h>

#define N_NODES 4096
#define D_MODEL 256
#define NWORDS 128   // bitmap words per row (4096/32)
#define MAXC 512     // max neighbors per row (avg ~33; Poisson tail safe)

typedef __attribute__((ext_vector_type(8))) short short8;
typedef __attribute__((ext_vector_type(4))) float f32x4;

__device__ __forceinline__ unsigned short f2b(float f) {  // fp32 -> bf16 RTN
    unsigned u = __float_as_uint(f);
    return (unsigned short)((u + 0x7FFFu + ((u >> 16) & 1u)) >> 16);
}
__device__ __forceinline__ float b2f(unsigned short u) {
    return __uint_as_float((unsigned)u << 16);
}

// ---------------- fast zero (hipMemsetAsync's fill kernel ran at 49 GB/s) --
__global__ __launch_bounds__(256) void zero_kernel(uint4* __restrict__ p) {
    p[(size_t)blockIdx.x * 256 + threadIdx.x] = uint4{0, 0, 0, 0};
}

// ---------------- LayerNorm: one block (256 thr) per row, bf16 out -------
__global__ __launch_bounds__(256) void ln_kernel(const float* __restrict__ x,
                                                 const float* __restrict__ g,
                                                 const float* __restrict__ b,
                                                 unsigned short* __restrict__ out) {
    int row = blockIdx.x, t = threadIdx.x;
    float v = x[row * D_MODEL + t];
    __shared__ float red[4];
    float s = v;
    #pragma unroll
    for (int off = 32; off; off >>= 1) s += __shfl_down(s, off, 64);
    if ((t & 63) == 0) red[t >> 6] = s;
    __syncthreads();
    float mu = (red[0] + red[1] + red[2] + red[3]) * (1.0f / 256.0f);
    __syncthreads();
    float d = v - mu;
    float s2 = d * d;
    #pragma unroll
    for (int off = 32; off; off >>= 1) s2 += __shfl_down(s2, off, 64);
    if ((t & 63) == 0) red[t >> 6] = s2;
    __syncthreads();
    float var = (red[0] + red[1] + red[2] + red[3]) * (1.0f / 256.0f);
    out[row * D_MODEL + t] = f2b(d * rsqrtf(var + 1e-5f) * g[t] + b[t]);
}

// ---------------- edge dtype detect: int64 arrays have 0 high words ------
__global__ void detect_kernel(const int* __restrict__ ei, int* __restrict__ flag) {
    if (threadIdx.x == 0 && blockIdx.x == 0) {
        int is64 = 1;
        for (int i = 1; i < 128; i += 2)
            if (ei[i] != 0) { is64 = 0; break; }
        *flag = is64;
    }
}

// ---------------- build dedup'd adjacency bitmap --------------------------
__global__ __launch_bounds__(256) void build_adj(const int* __restrict__ ei, int E,
                                                 const int* __restrict__ flag,
                                                 unsigned* __restrict__ bitmap) {
    int e = blockIdx.x * blockDim.x + threadIdx.x;
    if (e >= E) return;
    int n, m;
    if (*flag) { n = ei[2 * e]; m = ei[2 * (E + e)]; }
    else       { n = ei[e];     m = ei[E + e]; }
    atomicOr(&bitmap[n * NWORDS + (m >> 5)], 1u << (m & 31));
}

// ---------------- bitmap -> CSR (order-preserving, deterministic) ---------
__global__ __launch_bounds__(128) void csr_kernel(const unsigned* __restrict__ bitmap,
                                                  int* __restrict__ csr,
                                                  int* __restrict__ cnt) {
    int row = blockIdx.x, t = threadIdx.x;   // t = word index 0..127
    unsigned word = bitmap[row * NWORDS + t];
    int pc = __popc(word);
    int pre = pc;                             // inclusive prefix within wave
    #pragma unroll
    for (int off = 1; off < 64; off <<= 1) {
        int u = __shfl_up(pre, off, 64);
        if ((t & 63) >= off) pre += u;
    }
    __shared__ int wsum[2];
    if ((t & 63) == 63) wsum[t >> 6] = pre;
    __syncthreads();
    int base = (t >= 64) ? wsum[0] : 0;
    int off = base + pre - pc;                // exclusive prefix across 128
    int* dst = csr + (size_t)row * MAXC;
    while (word) {
        int bit = __ffs(word) - 1;
        word &= word - 1;
        if (off < MAXC) dst[off] = (t << 5) + bit;
        ++off;
    }
    if (t == 127) cnt[row] = min(base + pre, MAXC);
}

// ---------------- weights: fp32 [K][M] -> bf16 transposed [M][K] ----------
__global__ __launch_bounds__(256) void convw_kernel(const float* __restrict__ Wq,
        const float* __restrict__ Wk, const float* __restrict__ Wv,
        const float* __restrict__ Wo, const float* __restrict__ Wm1,
        const float* __restrict__ Wm2, unsigned short* __restrict__ wbf) {
    int e = blockIdx.x * 256 + threadIdx.x;   // 0..524287
    const float* W; int base, K, M;
    if (e < 262144) {
        int r = e >> 16;
        W = (r == 0) ? Wq : (r == 1) ? Wk : (r == 2) ? Wv : Wo;
        base = r << 16; K = 256; M = 256;
    } else if (e < 393216) { W = Wm1; base = 262144; K = 256; M = 512; }
    else                   { W = Wm2; base = 393216; K = 512; M = 256; }
    int i = e - base;
    int m = i / K, k = i - m * K;
    wbf[e] = f2b(W[k * M + m]);   // WT[m][k], row-major [M][K]
}

// ---------------- bf16 MFMA GEMM ------------------------------------------
// A:[rows][K] bf16. BT:[M][K] bf16. 64x64 tile, BK=32, 4 waves of 32x32.
// MODE 0: +bias -> f32 | 1: +bias,GELU -> bf16 | 2: +bias+R -> f32
// MODE 3: qkv 3-part bias -> bf16
template <int MODE>
__global__ __launch_bounds__(256) void gemm_bf16(const unsigned short* __restrict__ A,
        const unsigned short* __restrict__ BT, const float* __restrict__ bias,
        const float* __restrict__ bias_k, const float* __restrict__ bias_v,
        const float* __restrict__ R, float* __restrict__ Cf,
        unsigned short* __restrict__ Cb, int K, int M) {
    __shared__ unsigned short Al[64][40];
    __shared__ unsigned short Bl[64][40];
    int tid = threadIdx.x;
    int brow = blockIdx.x * 64, bcol = blockIdx.y * 64;
    int wid = tid >> 6, lane = tid & 63;
    int wr = wid >> 1, wc = wid & 1;
    int l15 = lane & 15, lhi = lane >> 4;
    int srow = tid >> 2, scol = (tid & 3) << 3;
    const unsigned short* Ap = A + (size_t)(brow + srow) * K + scol;
    const unsigned short* Bp = BT + (size_t)(bcol + srow) * K + scol;
    f32x4 acc[2][2] = {};
    for (int k0 = 0; k0 < K; k0 += 32) {
        short8 av = *(const short8*)(Ap + k0);
        short8 bv = *(const short8*)(Bp + k0);
        *(short8*)&Al[srow][scol] = av;
        *(short8*)&Bl[srow][scol] = bv;
        __syncthreads();
        short8 a0 = *(const short8*)&Al[wr * 32 + l15][lhi * 8];
        short8 a1 = *(const short8*)&Al[wr * 32 + 16 + l15][lhi * 8];
        short8 b0 = *(const short8*)&Bl[wc * 32 + l15][lhi * 8];
        short8 b1 = *(const short8*)&Bl[wc * 32 + 16 + l15][lhi * 8];
        acc[0][0] = __builtin_amdgcn_mfma_f32_16x16x32_bf16(a0, b0, acc[0][0], 0, 0, 0);
        acc[0][1] = __builtin_amdgcn_mfma_f32_16x16x32_bf16(a0, b1, acc[0][1], 0, 0, 0);
        acc[1][0] = __builtin_amdgcn_mfma_f32_16x16x32_bf16(a1, b0, acc[1][0], 0, 0, 0);
        acc[1][1] = __builtin_amdgcn_mfma_f32_16x16x32_bf16(a1, b1, acc[1][1], 0, 0, 0);
        __syncthreads();
    }
    #pragma unroll
    for (int sm = 0; sm < 2; ++sm)
        #pragma unroll
        for (int sn = 0; sn < 2; ++sn) {
            int col = bcol + wc * 32 + sn * 16 + l15;
            float bs;
            if (MODE == 3)
                bs = (col < 256) ? bias[col]
                   : (col < 512) ? bias_k[col - 256] : bias_v[col - 512];
            else
                bs = bias[col];
            #pragma unroll
            for (int r = 0; r < 4; ++r) {
                int row = brow + wr * 32 + sm * 16 + lhi * 4 + r;
                float c = acc[sm][sn][r] + bs;
                if (MODE == 1) {
                    c = 0.5f * c * (1.0f + erff(c * 0.70710678118654752f));
                    Cb[(size_t)row * M + col] = f2b(c);
                } else if (MODE == 2) {
                    Cf[(size_t)row * M + col] = c + R[(size_t)row * M + col];
                } else if (MODE == 3) {
                    Cb[(size_t)row * M + col] = f2b(c);
                } else {
                    Cf[(size_t)row * M + col] = c;
                }
            }
        }
}

// ---------------- sparse attention: lanes=neighbors, batch softmax --------
// qkv: [N][768] bf16 (q|k|v). 1 block/row, 8 head-groups of 32 lanes.
__global__ __launch_bounds__(256) void attn_kernel(const unsigned short* __restrict__ qkv,
        const int* __restrict__ csr, const int* __restrict__ cnt,
        unsigned short* __restrict__ y) {
    int n = blockIdx.x, tid = threadIdx.x;
    int h = tid >> 5, lane = tid & 31;
    int c = cnt[n];
    __shared__ int sIdx[MAXC];
    for (int i = tid; i < c; i += 256) sIdx[i] = csr[(size_t)n * MAXC + i];
    __syncthreads();

    const unsigned short* qp = qkv + (size_t)n * 768 + h * 32;
    float qreg[32];
    #pragma unroll
    for (int i = 0; i < 4; ++i) {
        short8 q8 = *(const short8*)(qp + i * 8);
        #pragma unroll
        for (int j = 0; j < 8; ++j) qreg[i * 8 + j] = b2f((unsigned short)q8[j]);
    }
    const float sc = 0.17677669529663687f;   // 1/sqrt(32)
    float m_run = -INFINITY, S = 0.0f, acc = 0.0f;
    for (int b0 = 0; b0 < c; b0 += 32) {
        int j = b0 + lane;
        float s = -INFINITY;
        if (j < c) {
            const unsigned short* kp = qkv + (size_t)sIdx[j] * 768 + 256 + h * 32;
            float d = 0.0f;
            #pragma unroll
            for (int i = 0; i < 4; ++i) {
                short8 k8 = *(const short8*)(kp + i * 8);
                #pragma unroll
                for (int e = 0; e < 8; ++e)
                    d = fmaf(qreg[i * 8 + e], b2f((unsigned short)k8[e]), d);
            }
            s = d * sc;
        }
        float bm = s;
        #pragma unroll
        for (int off = 16; off; off >>= 1) bm = fmaxf(bm, __shfl_xor(bm, off, 32));
        float newM = fmaxf(m_run, bm);
        float p = (j < c) ? __expf(s - newM) : 0.0f;
        float bs = p;
        #pragma unroll
        for (int off = 16; off; off >>= 1) bs += __shfl_xor(bs, off, 32);
        float scale = __expf(m_run - newM);
        S = S * scale + bs;
        acc *= scale;
        int lim = min(32, c - b0);
        const unsigned short* vbase = qkv + 512 + h * 32 + lane;
        #pragma unroll 4
        for (int jj = 0; jj < lim; ++jj) {
            float pj = __shfl(p, jj, 32);
            int m = sIdx[b0 + jj];
            acc = fmaf(pj, b2f(vbase[(size_t)m * 768]), acc);
        }
        m_run = newM;
    }
    y[(size_t)n * 256 + h * 32 + lane] = f2b(acc / S);
}

extern "C" void kernel_launch(void* const* d_in, const int* in_sizes, int n_in,
                              void* d_out, int out_size, void* d_ws, size_t ws_size,
                              hipStream_t stream) {
    const float* x   = (const float*)d_in[0];
    const int*   ei  = (const int*)d_in[1];
    const float* Wq  = (const float*)d_in[2];  const float* bq  = (const float*)d_in[3];
    const float* Wk  = (const float*)d_in[4];  const float* bk  = (const float*)d_in[5];
    const float* Wv  = (const float*)d_in[6];  const float* bv  = (const float*)d_in[7];
    const float* Wo  = (const float*)d_in[8];  const float* bo  = (const float*)d_in[9];
    const float* g1  = (const float*)d_in[10]; const float* b1  = (const float*)d_in[11];
    const float* g2  = (const float*)d_in[12]; const float* b2  = (const float*)d_in[13];
    const float* Wm1 = (const float*)d_in[14]; const float* bm1 = (const float*)d_in[15];
    const float* Wm2 = (const float*)d_in[16]; const float* bm2 = (const float*)d_in[17];
    float* out = (float*)d_out;
    int E = in_sizes[1] / 2;   // 135168

    char* WS = (char*)d_ws;
    const size_t MB = 1u << 20;
    unsigned*       bitmap = (unsigned*)WS;                     // [0,2MB), later y
    unsigned short* y      = (unsigned short*)WS;               // reuse after csr
    int*            flag   = (int*)(WS + 2 * MB);               // 4B
    int*            cnt    = (int*)(WS + 2 * MB + 4096);        // 16KB
    unsigned short* wbf    = (unsigned short*)(WS + 3 * MB);    // 1MB
    int*            csr    = (int*)(WS + 4 * MB);               // 8MB, later x1/m1
    float*          x1     = (float*)(WS + 4 * MB);             // 4MB (post-attn)
    unsigned short* m1     = (unsigned short*)(WS + 8 * MB);    // 4MB (post-attn)
    unsigned short* h      = (unsigned short*)(WS + 12 * MB);   // 2MB, later h2
    unsigned short* h2     = (unsigned short*)(WS + 12 * MB);
    unsigned short* qkv    = (unsigned short*)(WS + 14 * MB);   // 6MB

    const unsigned short* WTqkv = wbf;            // q|k|v stacked along M
    const unsigned short* WTo   = wbf + 196608;
    const unsigned short* WTm1  = wbf + 262144;
    const unsigned short* WTm2  = wbf + 393216;

    zero_kernel<<<512, 256, 0, stream>>>((uint4*)bitmap);   // 2MB in ~1-2us
    detect_kernel<<<1, 64, 0, stream>>>(ei, flag);
    convw_kernel<<<2048, 256, 0, stream>>>(Wq, Wk, Wv, Wo, Wm1, Wm2, wbf);
    ln_kernel<<<N_NODES, 256, 0, stream>>>(x, g1, b1, h);
    build_adj<<<(E + 255) / 256, 256, 0, stream>>>(ei, E, flag, bitmap);
    csr_kernel<<<N_NODES, 128, 0, stream>>>(bitmap, csr, cnt);

    dim3 gqkv(N_NODES / 64, 12), g256(N_NODES / 64, 4), g512(N_NODES / 64, 8);
    gemm_bf16<3><<<gqkv, 256, 0, stream>>>(h, WTqkv, bq, bk, bv, nullptr,
                                           nullptr, qkv, 256, 768);

    attn_kernel<<<N_NODES, 256, 0, stream>>>(qkv, csr, cnt, y);

    gemm_bf16<2><<<g256, 256, 0, stream>>>(y, WTo, bo, nullptr, nullptr, x,
                                           x1, nullptr, 256, 256);
    ln_kernel<<<N_NODES, 256, 0, stream>>>(x1, g2, b2, h2);
    gemm_bf16<1><<<g512, 256, 0, stream>>>(h2, WTm1, bm1, nullptr, nullptr, nullptr,
                                           nullptr, m1, 256, 512);
    gemm_bf16<2><<<g256, 256, 0, stream>>>(m1, WTm2, bm2, nullptr, nullptr, x1,
                                           out, nullptr, 512, 256);
}

// Round 5
// 92.863 us; speedup vs baseline: 2.2975x; 1.1393x over previous
//
#include <hip/hip_runtime.h>
#include <hip/hip_bf16.h>

#define N_NODES 4096
#define D_MODEL 256
#define NWORDS 128   // bitmap words per row (4096/32)
#define MAXC 512     // max neighbors per row (avg ~33)

typedef __attribute__((ext_vector_type(8))) short short8;
typedef __attribute__((ext_vector_type(4))) float f32x4;

__device__ __forceinline__ unsigned short f2b(float f) {  // fp32 -> bf16 RTN
    unsigned u = __float_as_uint(f);
    return (unsigned short)((u + 0x7FFFu + ((u >> 16) & 1u)) >> 16);
}
__device__ __forceinline__ float b2f(unsigned short u) {
    return __uint_as_float((unsigned)u << 16);
}

// ---------------- prep: convw (blocks 0..2047) | zero bitmap (2048..2559)
// ---------------- | detect (2560) -------------------------------------
__global__ __launch_bounds__(256) void prep_kernel(const float* __restrict__ Wq,
        const float* __restrict__ Wk, const float* __restrict__ Wv,
        const float* __restrict__ Wo, const float* __restrict__ Wm1,
        const float* __restrict__ Wm2, unsigned short* __restrict__ wbf,
        uint4* __restrict__ bitmap, const int* __restrict__ ei,
        int* __restrict__ flag) {
    int b = blockIdx.x;
    if (b < 2048) {                       // weight fp32 [K][M] -> bf16 [M][K]
        int e = b * 256 + threadIdx.x;    // 0..524287
        const float* W; int base, K, M;
        if (e < 262144) {
            int r = e >> 16;
            W = (r == 0) ? Wq : (r == 1) ? Wk : (r == 2) ? Wv : Wo;
            base = r << 16; K = 256; M = 256;
        } else if (e < 393216) { W = Wm1; base = 262144; K = 256; M = 512; }
        else                   { W = Wm2; base = 393216; K = 512; M = 256; }
        int i = e - base;
        int m = i / K, k = i - m * K;
        wbf[e] = f2b(W[k * M + m]);
    } else if (b < 2560) {                // zero the 2MB bitmap
        bitmap[(size_t)(b - 2048) * 256 + threadIdx.x] = uint4{0, 0, 0, 0};
    } else if (threadIdx.x == 0) {        // edge dtype detect
        int is64 = 1;
        for (int i = 1; i < 128; i += 2)
            if (ei[i] != 0) { is64 = 0; break; }
        *flag = is64;
    }
}

// ---------------- LayerNorm: one block (256 thr) per row, bf16 out -------
__global__ __launch_bounds__(256) void ln_kernel(const float* __restrict__ x,
                                                 const float* __restrict__ g,
                                                 const float* __restrict__ b,
                                                 unsigned short* __restrict__ out) {
    int row = blockIdx.x, t = threadIdx.x;
    float v = x[row * D_MODEL + t];
    __shared__ float red[4];
    float s = v;
    #pragma unroll
    for (int off = 32; off; off >>= 1) s += __shfl_down(s, off, 64);
    if ((t & 63) == 0) red[t >> 6] = s;
    __syncthreads();
    float mu = (red[0] + red[1] + red[2] + red[3]) * (1.0f / 256.0f);
    __syncthreads();
    float d = v - mu;
    float s2 = d * d;
    #pragma unroll
    for (int off = 32; off; off >>= 1) s2 += __shfl_down(s2, off, 64);
    if ((t & 63) == 0) red[t >> 6] = s2;
    __syncthreads();
    float var = (red[0] + red[1] + red[2] + red[3]) * (1.0f / 256.0f);
    out[row * D_MODEL + t] = f2b(d * rsqrtf(var + 1e-5f) * g[t] + b[t]);
}

// ---------------- build dedup'd adjacency bitmap --------------------------
__global__ __launch_bounds__(256) void build_adj(const int* __restrict__ ei, int E,
                                                 const int* __restrict__ flag,
                                                 unsigned* __restrict__ bitmap) {
    int e = blockIdx.x * blockDim.x + threadIdx.x;
    if (e >= E) return;
    int n, m;
    if (*flag) { n = ei[2 * e]; m = ei[2 * (E + e)]; }
    else       { n = ei[e];     m = ei[E + e]; }
    atomicOr(&bitmap[n * NWORDS + (m >> 5)], 1u << (m & 31));
}

// ---------------- bf16 MFMA GEMM, BK=64 -----------------------------------
// A:[rows][K] bf16. BT:[M][K] bf16. 64x64 tile, 4 waves of 32x32.
// MODE 1: +bias,GELU -> bf16 | 2: +bias+R -> f32 | 3: qkv 3-part bias -> bf16
template <int MODE>
__global__ __launch_bounds__(256) void gemm_bf16(const unsigned short* __restrict__ A,
        const unsigned short* __restrict__ BT, const float* __restrict__ bias,
        const float* __restrict__ bias_k, const float* __restrict__ bias_v,
        const float* __restrict__ R, float* __restrict__ Cf,
        unsigned short* __restrict__ Cb, int K, int M) {
    __shared__ unsigned short Al[64][72];   // stride 72 shorts = 36 dwords
    __shared__ unsigned short Bl[64][72];
    int tid = threadIdx.x;
    int brow = blockIdx.x * 64, bcol = blockIdx.y * 64;
    int wid = tid >> 6, lane = tid & 63;
    int wr = wid >> 1, wc = wid & 1;
    int l15 = lane & 15, lhi = lane >> 4;
    int r0 = tid >> 3, c0 = (tid & 7) << 3;   // staging slot 0 (rows 0..31)
    int r1 = r0 + 32;                          // staging slot 1 (rows 32..63)
    const unsigned short* Ap0 = A + (size_t)(brow + r0) * K + c0;
    const unsigned short* Ap1 = A + (size_t)(brow + r1) * K + c0;
    const unsigned short* Bp0 = BT + (size_t)(bcol + r0) * K + c0;
    const unsigned short* Bp1 = BT + (size_t)(bcol + r1) * K + c0;
    f32x4 acc[2][2] = {};
    for (int k0 = 0; k0 < K; k0 += 64) {
        short8 a0v = *(const short8*)(Ap0 + k0);
        short8 a1v = *(const short8*)(Ap1 + k0);
        short8 b0v = *(const short8*)(Bp0 + k0);
        short8 b1v = *(const short8*)(Bp1 + k0);
        *(short8*)&Al[r0][c0] = a0v;
        *(short8*)&Al[r1][c0] = a1v;
        *(short8*)&Bl[r0][c0] = b0v;
        *(short8*)&Bl[r1][c0] = b1v;
        __syncthreads();
        #pragma unroll
        for (int ks = 0; ks < 2; ++ks) {
            int kc = ks * 32 + lhi * 8;
            short8 a_0 = *(const short8*)&Al[wr * 32 + l15][kc];
            short8 a_1 = *(const short8*)&Al[wr * 32 + 16 + l15][kc];
            short8 b_0 = *(const short8*)&Bl[wc * 32 + l15][kc];
            short8 b_1 = *(const short8*)&Bl[wc * 32 + 16 + l15][kc];
            acc[0][0] = __builtin_amdgcn_mfma_f32_16x16x32_bf16(a_0, b_0, acc[0][0], 0, 0, 0);
            acc[0][1] = __builtin_amdgcn_mfma_f32_16x16x32_bf16(a_0, b_1, acc[0][1], 0, 0, 0);
            acc[1][0] = __builtin_amdgcn_mfma_f32_16x16x32_bf16(a_1, b_0, acc[1][0], 0, 0, 0);
            acc[1][1] = __builtin_amdgcn_mfma_f32_16x16x32_bf16(a_1, b_1, acc[1][1], 0, 0, 0);
        }
        __syncthreads();
    }
    #pragma unroll
    for (int sm = 0; sm < 2; ++sm)
        #pragma unroll
        for (int sn = 0; sn < 2; ++sn) {
            int col = bcol + wc * 32 + sn * 16 + l15;
            float bs;
            if (MODE == 3)
                bs = (col < 256) ? bias[col]
                   : (col < 512) ? bias_k[col - 256] : bias_v[col - 512];
            else
                bs = bias[col];
            #pragma unroll
            for (int r = 0; r < 4; ++r) {
                int row = brow + wr * 32 + sm * 16 + lhi * 4 + r;
                float c = acc[sm][sn][r] + bs;
                if (MODE == 1) {
                    c = 0.5f * c * (1.0f + erff(c * 0.70710678118654752f));
                    Cb[(size_t)row * M + col] = f2b(c);
                } else if (MODE == 2) {
                    Cf[(size_t)row * M + col] = c + R[(size_t)row * M + col];
                } else {
                    Cb[(size_t)row * M + col] = f2b(c);
                }
            }
        }
}

// ---------------- sparse attention w/ inline bitmap->index scan -----------
// qkv: [N][768] bf16 (q|k|v). 1 block/row, 8 head-groups of 32 lanes.
__global__ __launch_bounds__(256) void attn_kernel(const unsigned short* __restrict__ qkv,
        const unsigned* __restrict__ bitmap, unsigned short* __restrict__ y) {
    int n = blockIdx.x, tid = threadIdx.x;
    __shared__ int sIdx[MAXC];
    __shared__ int wsum[2];
    __shared__ int scnt;
    unsigned word = 0; int pc = 0, pre = 0;
    if (tid < 128) {                       // popc prefix scan of 128 words
        word = bitmap[n * NWORDS + tid];
        pc = __popc(word);
        pre = pc;
        #pragma unroll
        for (int off = 1; off < 64; off <<= 1) {
            int u = __shfl_up(pre, off, 64);
            if ((tid & 63) >= off) pre += u;
        }
        if ((tid & 63) == 63) wsum[tid >> 6] = pre;
    }
    __syncthreads();
    if (tid < 128) {
        int base = (tid >= 64) ? wsum[0] : 0;
        int off = base + pre - pc;
        while (word) {
            int bit = __ffs(word) - 1;
            word &= word - 1;
            if (off < MAXC) sIdx[off] = (tid << 5) + bit;
            ++off;
        }
        if (tid == 127) scnt = min(base + pre, MAXC);
    }
    __syncthreads();
    int c = scnt;
    int h = tid >> 5, lane = tid & 31;

    const unsigned short* qp = qkv + (size_t)n * 768 + h * 32;
    float qreg[32];
    #pragma unroll
    for (int i = 0; i < 4; ++i) {
        short8 q8 = *(const short8*)(qp + i * 8);
        #pragma unroll
        for (int j = 0; j < 8; ++j) qreg[i * 8 + j] = b2f((unsigned short)q8[j]);
    }
    const float sc = 0.17677669529663687f;   // 1/sqrt(32)
    float m_run = -INFINITY, S = 0.0f, acc = 0.0f;
    for (int b0 = 0; b0 < c; b0 += 32) {
        int j = b0 + lane;
        float s = -INFINITY;
        if (j < c) {
            const unsigned short* kp = qkv + (size_t)sIdx[j] * 768 + 256 + h * 32;
            float d = 0.0f;
            #pragma unroll
            for (int i = 0; i < 4; ++i) {
                short8 k8 = *(const short8*)(kp + i * 8);
                #pragma unroll
                for (int e = 0; e < 8; ++e)
                    d = fmaf(qreg[i * 8 + e], b2f((unsigned short)k8[e]), d);
            }
            s = d * sc;
        }
        float bm = s;
        #pragma unroll
        for (int off = 16; off; off >>= 1) bm = fmaxf(bm, __shfl_xor(bm, off, 32));
        float newM = fmaxf(m_run, bm);
        float p = (j < c) ? __expf(s - newM) : 0.0f;
        float bs = p;
        #pragma unroll
        for (int off = 16; off; off >>= 1) bs += __shfl_xor(bs, off, 32);
        float scale = __expf(m_run - newM);
        S = S * scale + bs;
        acc *= scale;
        int lim = min(32, c - b0);
        const unsigned short* vbase = qkv + 512 + h * 32 + lane;
        #pragma unroll 4
        for (int jj = 0; jj < lim; ++jj) {
            float pj = __shfl(p, jj, 32);
            int m = sIdx[b0 + jj];
            acc = fmaf(pj, b2f(vbase[(size_t)m * 768]), acc);
        }
        m_run = newM;
    }
    y[(size_t)n * 256 + h * 32 + lane] = f2b(acc / S);
}

extern "C" void kernel_launch(void* const* d_in, const int* in_sizes, int n_in,
                              void* d_out, int out_size, void* d_ws, size_t ws_size,
                              hipStream_t stream) {
    const float* x   = (const float*)d_in[0];
    const int*   ei  = (const int*)d_in[1];
    const float* Wq  = (const float*)d_in[2];  const float* bq  = (const float*)d_in[3];
    const float* Wk  = (const float*)d_in[4];  const float* bk  = (const float*)d_in[5];
    const float* Wv  = (const float*)d_in[6];  const float* bv  = (const float*)d_in[7];
    const float* Wo  = (const float*)d_in[8];  const float* bo  = (const float*)d_in[9];
    const float* g1  = (const float*)d_in[10]; const float* b1  = (const float*)d_in[11];
    const float* g2  = (const float*)d_in[12]; const float* b2  = (const float*)d_in[13];
    const float* Wm1 = (const float*)d_in[14]; const float* bm1 = (const float*)d_in[15];
    const float* Wm2 = (const float*)d_in[16]; const float* bm2 = (const float*)d_in[17];
    float* out = (float*)d_out;
    int E = in_sizes[1] / 2;   // 135168

    char* WS = (char*)d_ws;
    const size_t MB = 1u << 20;
    unsigned*       bitmap = (unsigned*)WS;                     // [0,2MB)
    int*            flag   = (int*)(WS + 2 * MB);               // 4B
    unsigned short* wbf    = (unsigned short*)(WS + 3 * MB);    // 1MB
    unsigned short* y      = (unsigned short*)(WS + 4 * MB);    // 2MB
    float*          x1     = (float*)(WS + 6 * MB);             // 4MB
    unsigned short* m1     = (unsigned short*)(WS + 10 * MB);   // 4MB
    unsigned short* h      = (unsigned short*)(WS + 14 * MB);   // 2MB (h, then h2)
    unsigned short* qkv    = (unsigned short*)(WS + 16 * MB);   // 6MB

    const unsigned short* WTqkv = wbf;            // q|k|v stacked along M
    const unsigned short* WTo   = wbf + 196608;
    const unsigned short* WTm1  = wbf + 262144;
    const unsigned short* WTm2  = wbf + 393216;

    prep_kernel<<<2561, 256, 0, stream>>>(Wq, Wk, Wv, Wo, Wm1, Wm2, wbf,
                                          (uint4*)bitmap, ei, flag);
    ln_kernel<<<N_NODES, 256, 0, stream>>>(x, g1, b1, h);
    build_adj<<<(E + 255) / 256, 256, 0, stream>>>(ei, E, flag, bitmap);

    dim3 gqkv(N_NODES / 64, 12), g256(N_NODES / 64, 4), g512(N_NODES / 64, 8);
    gemm_bf16<3><<<gqkv, 256, 0, stream>>>(h, WTqkv, bq, bk, bv, nullptr,
                                           nullptr, qkv, 256, 768);

    attn_kernel<<<N_NODES, 256, 0, stream>>>(qkv, bitmap, y);

    gemm_bf16<2><<<g256, 256, 0, stream>>>(y, WTo, bo, nullptr, nullptr, x,
                                           x1, nullptr, 256, 256);
    ln_kernel<<<N_NODES, 256, 0, stream>>>(x1, g2, b2, h);
    gemm_bf16<1><<<g512, 256, 0, stream>>>(h, WTm1, bm1, nullptr, nullptr, nullptr,
                                           nullptr, m1, 256, 512);
    gemm_bf16<2><<<g256, 256, 0, stream>>>(m1, WTm2, bm2, nullptr, nullptr, x1,
                                           out, nullptr, 512, 256);
}